// Round 7
// baseline (18.818 us; speedup 1.0000x reference)
//
#include <hip/hip_runtime.h>

// Problem constants (from reference)
#define O_NUM 256
#define IN_NUM 768
#define NS 32            // B*R = 8*4 samples
#define L0 128
#define L1 22
#define L2 4
// Padded LDS row strides (odd -> conflict-free for sample-strided access)
#define Y0S 133          // >= L1*6 = 132
#define Y1S 25           // >= L2*6 = 24

// (tanh(w)+1)/2 == sigmoid(2w) == 1/(1 + 2^(-2*log2(e)*w))
__device__ __forceinline__ float fast_sig2(float w) {
    float e = __builtin_amdgcn_exp2f(w * -2.8853900817779268f);
    return __builtin_amdgcn_rcpf(1.0f + e);
}
__device__ __forceinline__ float4 sig4(float4 q) {
    float4 r = { fast_sig2(q.x), fast_sig2(q.y), fast_sig2(q.z), fast_sig2(q.w) };
    return r;
}

// 6-level LUT tree, weights pre-split: we[j]=w[2j], dd[j]=w[2j+1]-w[2j].
__device__ __forceinline__ float lut6_wd(const float* __restrict__ we,
                                         const float* __restrict__ dd,
                                         const float* __restrict__ b) {
    float v[32];
#pragma unroll
    for (int j = 0; j < 32; ++j)
        v[j] = fmaf(b[0], dd[j], we[j]);
#pragma unroll
    for (int lvl = 1; lvl < 6; ++lvl) {
        const int n = 32 >> lvl;
#pragma unroll
        for (int j = 0; j < n; ++j)
            v[j] = fmaf(b[lvl], v[2 * j + 1] - v[2 * j], v[2 * j]);
    }
    return v[0];
}

// Load a 64-float LDS row into we/dd form via ds_read_b128.
__device__ __forceinline__ void load_row_wd(const float* __restrict__ src,
                                            float* __restrict__ we, float* __restrict__ dd) {
    const float4* p = (const float4*)src;   // rows are 256B-aligned
#pragma unroll
    for (int k = 0; k < 16; ++k) {
        float4 q = p[k];
        we[2 * k]     = q.x; dd[2 * k]     = q.y - q.x;
        we[2 * k + 1] = q.z; dd[2 * k + 1] = q.w - q.z;
    }
}

__global__ __launch_bounds__(512) void lut_quant_fc_kernel(
    const float* __restrict__ x,    // [NS][IN_NUM]
    const float* __restrict__ w0,   // [O_NUM][L0][64]
    const float* __restrict__ w1,   // [O_NUM][L1][64]
    const float* __restrict__ w2,   // [O_NUM][L2][64]
    const float* __restrict__ w3,   // [O_NUM][1][64]
    float* __restrict__ out)        // [NS][O_NUM]
{
    const int o = blockIdx.x;
    const int tid = threadIdx.x;

    __shared__ float4 sw0[L0 * 16];  // 32 KB, XOR-swizzled transformed w0 rows
    __shared__ float wq1[L1 * 64];   // 5.5 KB
    __shared__ float wq2[L2 * 64];   // 1 KB
    __shared__ float wq3[64];
    __shared__ float y0[NS * Y0S];   // ~17 KB
    __shared__ float y1[NS * Y1S];   // ~3.1 KB

    const int l  = tid & 127;        // cell 0..127
    const int sg = tid >> 7;         // sample group 0..3 (8 samples each)

    // ---- Phase A: x prefetch (registers) || w0 staging (LDS) ----
    // x loads issue first and complete under the w0 fetch+transform.
    float2 xp[8][3];
#pragma unroll
    for (int i = 0; i < 8; ++i) {
        const int s = sg * 8 + i;
        const float2* xb = (const float2*)(x + (size_t)s * IN_NUM + l * 6);  // 8B-aligned
        xp[i][0] = xb[0]; xp[i][1] = xb[1]; xp[i][2] = xb[2];
    }
    {
        const float4* g = (const float4*)(w0 + (size_t)o * (L0 * 64));
#pragma unroll
        for (int r = 0; r < 4; ++r) {
            int idx = r * 512 + tid;            // coalesced
            float4 t = sig4(g[idx]);
            int lw = idx >> 4, kw = idx & 15;
            sw0[lw * 16 + (kw ^ (lw & 15))] = t;   // XOR-swizzled store
        }
    }
    if (tid < NS * 4) {                          // y0 pad cols 128..131 = 0
        int s = tid >> 2;
        y0[s * Y0S + L0 + (tid & 3)] = 0.0f;
    }
    if (tid < NS * 2) {                          // y1 pad cols 22..23 = 0
        int s = tid >> 1;
        y1[s * Y1S + L1 + (tid & 1)] = 0.0f;
    }
    __syncthreads();                             // sw0 + pads ready

    // ---- Phase B: issue w1/w2/w3 loads, compute layer 0 (hides latency),
    //      then transform+store w1/w2/w3 ----
    float4 q123;
    if (tid < 352)       q123 = ((const float4*)(w1 + (size_t)o * (L1 * 64)))[tid];
    else if (tid < 416)  q123 = ((const float4*)(w2 + (size_t)o * (L2 * 64)))[tid - 352];
    else if (tid < 432)  q123 = ((const float4*)(w3 + (size_t)o * 64))[tid - 416];

    float we[32], dd[32];
    {
        const int base = l * 16, sw = l & 15;
#pragma unroll
        for (int k = 0; k < 16; ++k) {
            float4 q = sw0[base + (k ^ sw)];
            we[2 * k]     = q.x; dd[2 * k]     = q.y - q.x;
            we[2 * k + 1] = q.z; dd[2 * k + 1] = q.w - q.z;
        }
    }
#pragma unroll 2
    for (int i = 0; i < 8; ++i) {
        const int s = sg * 8 + i;
        float b[6] = { xp[i][0].x, xp[i][0].y, xp[i][1].x, xp[i][1].y, xp[i][2].x, xp[i][2].y };
        y0[s * Y0S + l] = lut6_wd(we, dd, b);    // lane-consecutive write
    }

    if (tid < 352)       ((float4*)wq1)[tid]       = sig4(q123);
    else if (tid < 416)  ((float4*)wq2)[tid - 352] = sig4(q123);
    else if (tid < 432)  ((float4*)wq3)[tid - 416] = sig4(q123);
    __syncthreads();                             // y0 + wq1/2/3 ready

    // ---- Phase C: layer 1 — 32 x 22 = 704 tasks ----
    for (int t = tid; t < NS * L1; t += 512) {
        const int s = t & 31;
        const int c = t >> 5;
        float we1[32], dd1[32];
        load_row_wd(&wq1[c * 64], we1, dd1);     // half-wave broadcast rows
        float b[6];
#pragma unroll
        for (int j = 0; j < 6; ++j) b[j] = y0[s * Y0S + c * 6 + j];
        y1[s * Y1S + c] = lut6_wd(we1, dd1, b);
    }
    __syncthreads();                             // y1 ready

    // ---- Phase D: fused layers 2+3 — one thread per sample, bits in regs ----
    if (tid < NS) {
        const int s = tid;
        float bits[24];
#pragma unroll
        for (int j = 0; j < 24; ++j) bits[j] = y1[s * Y1S + j];
        float cc[6];
#pragma unroll
        for (int c2 = 0; c2 < 4; ++c2) {
            float we2[32], dd2[32];
            load_row_wd(&wq2[c2 * 64], we2, dd2);
            cc[c2] = lut6_wd(we2, dd2, &bits[c2 * 6]);
        }
        cc[4] = 0.0f; cc[5] = 0.0f;              // layer-3 pad bits
        float we3[32], dd3[32];
        load_row_wd(wq3, we3, dd3);
        out[(size_t)s * O_NUM + o] = lut6_wd(we3, dd3, cc);
    }
}

extern "C" void kernel_launch(void* const* d_in, const int* in_sizes, int n_in,
                              void* d_out, int out_size, void* d_ws, size_t ws_size,
                              hipStream_t stream) {
    const float* x  = (const float*)d_in[0];
    const float* w0 = (const float*)d_in[1];
    const float* w1 = (const float*)d_in[2];
    const float* w2 = (const float*)d_in[3];
    const float* w3 = (const float*)d_in[4];
    float* out = (float*)d_out;

    lut_quant_fc_kernel<<<dim3(O_NUM), dim3(512), 0, stream>>>(x, w0, w1, w2, w3, out);
}

// Round 8
// 12.713 us; speedup vs baseline: 1.4802x; 1.4802x over previous
//
#include <hip/hip_runtime.h>

// Problem constants (from reference)
#define O_NUM 256
#define IN_NUM 768
#define NS 32            // B*R = 8*4 samples
#define L0 128
#define L1 22
#define L2 4
// Padded LDS row strides (odd -> conflict-free for sample-strided access)
#define Y0S 133          // >= L1*6 = 132
#define Y1S 25           // >= L2*6 = 24

// (tanh(w)+1)/2 == sigmoid(2w) == 1/(1 + 2^(-2*log2(e)*w))
__device__ __forceinline__ float fast_sig2(float w) {
    float e = __builtin_amdgcn_exp2f(w * -2.8853900817779268f);
    return __builtin_amdgcn_rcpf(1.0f + e);
}
__device__ __forceinline__ float4 sig4(float4 q) {
    float4 r = { fast_sig2(q.x), fast_sig2(q.y), fast_sig2(q.z), fast_sig2(q.w) };
    return r;
}

// 6-level LUT tree, weights pre-split: we[j]=w[2j], dd[j]=w[2j+1]-w[2j].
__device__ __forceinline__ float lut6_wd(const float* __restrict__ we,
                                         const float* __restrict__ dd,
                                         const float* __restrict__ b) {
    float v[32];
#pragma unroll
    for (int j = 0; j < 32; ++j)
        v[j] = fmaf(b[0], dd[j], we[j]);
#pragma unroll
    for (int lvl = 1; lvl < 6; ++lvl) {
        const int n = 32 >> lvl;
#pragma unroll
        for (int j = 0; j < n; ++j)
            v[j] = fmaf(b[lvl], v[2 * j + 1] - v[2 * j], v[2 * j]);
    }
    return v[0];
}

// Load a 64-float LDS row into we/dd form via ds_read_b128.
__device__ __forceinline__ void load_row_wd(const float* __restrict__ src,
                                            float* __restrict__ we, float* __restrict__ dd) {
    const float4* p = (const float4*)src;   // rows are 256B-aligned
#pragma unroll
    for (int k = 0; k < 16; ++k) {
        float4 q = p[k];
        we[2 * k]     = q.x; dd[2 * k]     = q.y - q.x;
        we[2 * k + 1] = q.z; dd[2 * k + 1] = q.w - q.z;
    }
}

// 1024 threads, grid = 256 (one block per output channel o).
__global__ __launch_bounds__(1024) void lut_quant_fc_kernel(
    const float* __restrict__ x,    // [NS][IN_NUM]
    const float* __restrict__ w0,   // [O_NUM][L0][64]
    const float* __restrict__ w1,   // [O_NUM][L1][64]
    const float* __restrict__ w2,   // [O_NUM][L2][64]
    const float* __restrict__ w3,   // [O_NUM][1][64]
    float* __restrict__ out)        // [NS][O_NUM]
{
    const int o = blockIdx.x;
    const int tid = threadIdx.x;

    __shared__ float4 sw0[L0 * 16];  // 32 KB, XOR-swizzled transformed w0 rows
    __shared__ float wq1[L1 * 64];   // 5.5 KB
    __shared__ float wq2[L2 * 64];   // 1 KB
    __shared__ float wq3[64];
    __shared__ float y0[NS * Y0S];   // ~17 KB
    __shared__ float y1[NS * Y1S];   // ~3.1 KB

    // ---- Phase A: stage w0 (coalesced, sig2 once per weight, swizzled store)
    //      and w1/w2/w3 in parallel across the 1024 threads ----
    {
        const float4* g = (const float4*)(w0 + (size_t)o * (L0 * 64));
#pragma unroll
        for (int r = 0; r < 2; ++r) {
            int idx = r * 1024 + tid;            // 0..2047, coalesced
            float4 t = sig4(g[idx]);
            int lw = idx >> 4, kw = idx & 15;
            sw0[lw * 16 + (kw ^ (lw & 15))] = t;
        }
    }
    if (tid >= 512) {                            // second half stages w1/w2/w3
        int i = tid - 512;
        if (i < 352)       ((float4*)wq1)[i] = sig4(((const float4*)(w1 + (size_t)o * (L1 * 64)))[i]);
        else if (i < 416)  ((float4*)wq2)[i - 352] = sig4(((const float4*)(w2 + (size_t)o * (L2 * 64)))[i - 352]);
        else if (i < 432)  ((float4*)wq3)[i - 416] = sig4(((const float4*)(w3 + (size_t)o * 64))[i - 416]);
    } else {
        if (tid < NS * 4) {                      // y0 pad cols 128..131 = 0
            int s = tid >> 2;
            y0[s * Y0S + L0 + (tid & 3)] = 0.0f;
        }
        if (tid < NS * 2) {                      // y1 pad cols 22..23 = 0
            int s = tid >> 1;
            y1[s * Y1S + L1 + (tid & 1)] = 0.0f;
        }
    }
    __syncthreads();

    // ---- Phase B: layer 0 — thread = (cell l, sample-group sg of 4) ----
    {
        const int l  = tid & 127;                // cell (lane-consecutive)
        const int sg = tid >> 7;                 // 0..7, 4 samples each
        float we[32], dd[32];
        const int base = l * 16, sw = l & 15;
#pragma unroll
        for (int k = 0; k < 16; ++k) {
            float4 q = sw0[base + (k ^ sw)];
            we[2 * k]     = q.x; dd[2 * k]     = q.y - q.x;
            we[2 * k + 1] = q.z; dd[2 * k + 1] = q.w - q.z;
        }
#pragma unroll
        for (int i = 0; i < 4; ++i) {
            const int s = sg * 4 + i;
            const float2* xb = (const float2*)(x + (size_t)s * IN_NUM + l * 6);  // 8B-aligned
            float2 b01 = xb[0], b23 = xb[1], b45 = xb[2];
            float b[6] = { b01.x, b01.y, b23.x, b23.y, b45.x, b45.y };
            y0[s * Y0S + l] = lut6_wd(we, dd, b);
        }
    }
    __syncthreads();

    // ---- Phase C: layer 1 — 32 x 22 = 704 tasks, single pass ----
    if (tid < NS * L1) {
        const int s = tid & 31;
        const int c = tid >> 5;
        float we1[32], dd1[32];
        load_row_wd(&wq1[c * 64], we1, dd1);     // half-wave broadcast rows
        float b[6];
#pragma unroll
        for (int j = 0; j < 6; ++j) b[j] = y0[s * Y0S + c * 6 + j];
        y1[s * Y1S + c] = lut6_wd(we1, dd1, b);
    }
    __syncthreads();

    // ---- Phase D: fused layers 2+3 — one thread per sample ----
    if (tid < NS) {
        const int s = tid;
        float bits[24];
#pragma unroll
        for (int j = 0; j < 24; ++j) bits[j] = y1[s * Y1S + j];
        float cc[6];
#pragma unroll
        for (int c2 = 0; c2 < 4; ++c2) {
            float we2[32], dd2[32];
            load_row_wd(&wq2[c2 * 64], we2, dd2);
            cc[c2] = lut6_wd(we2, dd2, &bits[c2 * 6]);
        }
        cc[4] = 0.0f; cc[5] = 0.0f;              // layer-3 pad bits
        float we3[32], dd3[32];
        load_row_wd(wq3, we3, dd3);
        out[(size_t)s * O_NUM + o] = lut6_wd(we3, dd3, cc);
    }
}

extern "C" void kernel_launch(void* const* d_in, const int* in_sizes, int n_in,
                              void* d_out, int out_size, void* d_ws, size_t ws_size,
                              hipStream_t stream) {
    const float* x  = (const float*)d_in[0];
    const float* w0 = (const float*)d_in[1];
    const float* w1 = (const float*)d_in[2];
    const float* w2 = (const float*)d_in[3];
    const float* w3 = (const float*)d_in[4];
    float* out = (float*)d_out;

    lut_quant_fc_kernel<<<dim3(O_NUM), dim3(1024), 0, stream>>>(x, w0, w1, w2, w3, out);
}